// Round 6
// baseline (142.792 us; speedup 1.0000x reference)
//
#include <hip/hip_runtime.h>

constexpr int Bc = 8, Cc = 512, Hc = 8, Dc = 64, Nc = 1024;
constexpr size_t QSZ = (size_t)Bc * Hc * Nc * Dc;  // 4,194,304 elements
constexpr size_t XTSZ = (size_t)8192 * 512;        // = QSZ
constexpr size_t WTSZ = (size_t)1536 * 512;

typedef __attribute__((ext_vector_type(8))) short short8;
typedef __attribute__((ext_vector_type(4))) float f32x4;
typedef unsigned short ushort_t;
typedef unsigned int uint_t;

// ------------------------------------------------------------ bf16 helpers
__device__ __forceinline__ ushort_t f2bf(float x) {
  uint_t u = __float_as_uint(x);
  u += 0x7FFFu + ((u >> 16) & 1u);  // round-to-nearest-even
  return (ushort_t)(u >> 16);
}
__device__ __forceinline__ float bf2f(ushort_t h) {
  return __uint_as_float(((uint_t)h) << 16);
}

// ---------------------------------------------------------------- zero output
__global__ void zero_out_k(float* __restrict__ o) {
  int i = blockIdx.x * 256 + threadIdx.x;
  if (i < Bc * Cc) o[i] = 0.f;
}

// ------------------------------------------------- transpose+split x -> xt
__global__ __launch_bounds__(256) void conv_x(const float* __restrict__ x,
                                              ushort_t* __restrict__ xh,
                                              ushort_t* __restrict__ xl) {
  __shared__ float t[64][65];
  const int b = blockIdx.z, c0 = blockIdx.y * 64, n0 = blockIdx.x * 64;
  const int tid = threadIdx.x;
  const int lc = tid & 63, lr = tid >> 6;
#pragma unroll
  for (int i = 0; i < 16; ++i) {
    int cc = lr + i * 4;
    t[cc][lc] = x[((size_t)(b * 512 + c0 + cc)) * 1024 + n0 + lc];
  }
  __syncthreads();
#pragma unroll
  for (int i = 0; i < 16; ++i) {
    int nn = lr + i * 4;
    float v = t[lc][nn];  // = x[b][c0+lc][n0+nn]
    ushort_t h = f2bf(v);
    ushort_t lo = f2bf(v - bf2f(h));
    size_t o = ((size_t)(b * 1024 + n0 + nn)) * 512 + c0 + lc;
    xh[o] = h;
    xl[o] = lo;
  }
}

// ------------------------------------------------- transpose+split W -> wt
__global__ __launch_bounds__(256) void conv_w(const float* __restrict__ wq,
                                              ushort_t* __restrict__ wh,
                                              ushort_t* __restrict__ wl) {
  __shared__ float t[64][65];
  const int c0 = blockIdx.y * 64, j0 = blockIdx.x * 64;
  const int tid = threadIdx.x;
  const int lj = tid & 63, lr = tid >> 6;
#pragma unroll
  for (int i = 0; i < 16; ++i) {
    int cc = lr + i * 4;
    t[cc][lj] = wq[(size_t)(c0 + cc) * 1536 + j0 + lj];
  }
  __syncthreads();
#pragma unroll
  for (int i = 0; i < 16; ++i) {
    int jj = lr + i * 4;
    float v = t[lj][jj];  // = W[c0+lj][j0+jj]
    ushort_t h = f2bf(v);
    ushort_t lo = f2bf(v - bf2f(h));
    size_t o = (size_t)(j0 + jj) * 512 + c0 + lj;
    wh[o] = h;
    wl[o] = lo;
  }
}

// ------------------------------------------------------ async stage helper
__device__ __forceinline__ void stage_tile(ushort_t* lds, const ushort_t* g,
                                           int tid) {
  typedef const __attribute__((address_space(1))) unsigned int GU;
  typedef __attribute__((address_space(3))) unsigned int LU;
  {
    int l = tid, r = l >> 2, c = (l & 3) * 8;
    __builtin_amdgcn_global_load_lds((GU*)(g + (size_t)r * 512 + c),
                                     (LU*)(lds + (size_t)l * 8), 16, 0, 0);
  }
  {
    int l = tid + 256, r = l >> 2, c = (l & 3) * 8;
    __builtin_amdgcn_global_load_lds((GU*)(g + (size_t)r * 512 + c),
                                     (LU*)(lds + (size_t)l * 8), 16, 0, 0);
  }
}

// ---------------------------------------------------------------- QKV GEMM
__global__ __launch_bounds__(256) void qkv_gemm_mfma(
    const ushort_t* __restrict__ xth, const ushort_t* __restrict__ xtl,
    const ushort_t* __restrict__ wth, const ushort_t* __restrict__ wtl,
    const float* __restrict__ bias, float* __restrict__ vbuf,
    ushort_t* __restrict__ khi, ushort_t* __restrict__ klo,
    ushort_t* __restrict__ qhi, ushort_t* __restrict__ qlo) {
  __shared__ __align__(16) ushort_t Ah[128 * 32];
  __shared__ __align__(16) ushort_t Al[128 * 32];
  __shared__ __align__(16) ushort_t Bh[128 * 32];
  __shared__ __align__(16) ushort_t Bl[128 * 32];

  const int m0 = blockIdx.x * 128, j0 = blockIdx.y * 128;
  const int tid = threadIdx.x;
  const int w = tid >> 6, l = tid & 63;
  const int lr = l & 15, lg = l >> 4;
  const int wr = w >> 1, wc = w & 1;

  f32x4 acc[4][4];
#pragma unroll
  for (int i = 0; i < 4; ++i)
#pragma unroll
    for (int j = 0; j < 4; ++j) acc[i][j] = (f32x4){0.f, 0.f, 0.f, 0.f};

  const ushort_t* xa = xth + (size_t)m0 * 512;
  const ushort_t* xb = xtl + (size_t)m0 * 512;
  const ushort_t* wa = wth + (size_t)j0 * 512;
  const ushort_t* wb = wtl + (size_t)j0 * 512;

  for (int s = 0; s < 16; ++s) {
    const int k0 = s * 32;
    stage_tile(Ah, xa + k0, tid);
    stage_tile(Al, xb + k0, tid);
    stage_tile(Bh, wa + k0, tid);
    stage_tile(Bl, wb + k0, tid);
    __syncthreads();  // drains vmcnt -> tiles resident

    short8 ah[4], al[4], bh[4], bl[4];
#pragma unroll
    for (int mi = 0; mi < 4; ++mi) {
      int ro = (wr * 64 + mi * 16 + lr) * 32 + lg * 8;
      ah[mi] = *(const short8*)&Ah[ro];
      al[mi] = *(const short8*)&Al[ro];
    }
#pragma unroll
    for (int ji = 0; ji < 4; ++ji) {
      int ro = (wc * 64 + ji * 16 + lr) * 32 + lg * 8;
      bh[ji] = *(const short8*)&Bh[ro];
      bl[ji] = *(const short8*)&Bl[ro];
    }
#pragma unroll
    for (int mi = 0; mi < 4; ++mi)
#pragma unroll
      for (int ji = 0; ji < 4; ++ji) {
        acc[mi][ji] = __builtin_amdgcn_mfma_f32_16x16x32_bf16(
            ah[mi], bh[ji], acc[mi][ji], 0, 0, 0);
        acc[mi][ji] = __builtin_amdgcn_mfma_f32_16x16x32_bf16(
            ah[mi], bl[ji], acc[mi][ji], 0, 0, 0);
        acc[mi][ji] = __builtin_amdgcn_mfma_f32_16x16x32_bf16(
            al[mi], bh[ji], acc[mi][ji], 0, 0, 0);
      }
    __syncthreads();
  }

  const int which = j0 >> 9;
  const int hh = ((j0 >> 6) + wc) & 7;
  float bias_r[4];
#pragma unroll
  for (int ji = 0; ji < 4; ++ji) bias_r[ji] = bias[j0 + wc * 64 + ji * 16 + lr];

#pragma unroll
  for (int mi = 0; mi < 4; ++mi)
#pragma unroll
    for (int t = 0; t < 4; ++t) {
      int m = m0 + wr * 64 + mi * 16 + lg * 4 + t;
      int b = m >> 10, n = m & 1023;
      size_t rb = ((size_t)(b * 8 + hh) << 16) + (size_t)n * 64;
#pragma unroll
      for (int ji = 0; ji < 4; ++ji) {
        float val = acc[mi][ji][t] + bias_r[ji];
        int dd = ji * 16 + lr;
        if (which == 2) {
          vbuf[rb + dd] = val;
        } else {
          ushort_t h = f2bf(val);
          ushort_t lo = f2bf(val - bf2f(h));
          if (which == 0) {
            qhi[rb + dd] = h;
            qlo[rb + dd] = lo;
          } else {
            khi[rb + dd] = h;
            klo[rb + dd] = lo;
          }
        }
      }
    }
}

// ------------------------------------------------------- packed-key top-4
// key = (mono(score) & ~1023) | j. mono: monotone map fp32 -> u32.
// keep 4 largest keys, sorted desc: s3=max(s3,k) then bubble (7 max/min ops).
__device__ __forceinline__ uint_t mono_f32(float x) {
  uint_t u = __float_as_uint(x);
  return u ^ (((uint_t)((int)u >> 31)) | 0x80000000u);
}
__device__ __forceinline__ float unmono_f32(uint_t u) {
  uint_t v = (u & 0x80000000u) ? (u ^ 0x80000000u) : ~u;
  return __uint_as_float(v);
}
__device__ __forceinline__ void insk(uint_t k, uint_t& s0, uint_t& s1,
                                     uint_t& s2, uint_t& s3) {
  s3 = max(s3, k);
  uint_t t;
  t = max(s2, s3); s3 = min(s2, s3); s2 = t;
  t = max(s1, s2); s2 = min(s1, s2); s1 = t;
  t = max(s0, s1); s1 = min(s0, s1); s0 = t;
}

// ---------------------------------------------------------------- fused attn
// grid = 1024 (bh = bid&63 -> same-bh blocks share an XCD; rg = bid>>6).
// 512 thr = 8 waves: (w>>2) = 32-row half (2 rowsets = R3 ILP shape),
// (w&3) = 256-wide j-quarter. Packed-key lane-local top-4, shfl merge,
// LDS merge across quarters, softmax, V-gather.
__global__ __launch_bounds__(512, 6) void attn_topk_mfma(
    const ushort_t* __restrict__ khi, const ushort_t* __restrict__ klo,
    const ushort_t* __restrict__ qhi, const ushort_t* __restrict__ qlo,
    const float* __restrict__ vg, float* __restrict__ out) {
  __shared__ uint_t kL[4][64][4];
  __shared__ float wgt[64][4];
  __shared__ int widx[64][4];
  __shared__ float accb[8][64];

  const int bid = blockIdx.x;
  const int bh = bid & 63;
  const int rg = bid >> 6;
  const int tid = threadIdx.x;
  const int w = tid >> 6, l = tid & 63;
  const int lg = l >> 4, lr = l & 15;
  const int jq = w & 3, rowhalf = w >> 2;

  const int bhbase = bh << 16;  // bh * 1024 * 64 (fits int)
  const int rowbase = rg * 64 + rowhalf * 32;

  // Q fragments: 2 rowsets x 2 d-chunks, hi & lo
  short8 qh[2][2], ql[2][2];
#pragma unroll
  for (int rs = 0; rs < 2; ++rs)
#pragma unroll
    for (int c = 0; c < 2; ++c) {
      int a = bhbase + (rowbase + rs * 16 + lr) * 64 + c * 32 + lg * 8;
      qh[rs][c] = *(const short8*)(qhi + a);
      ql[rs][c] = *(const short8*)(qlo + a);
    }

  uint_t K[2][4];
#pragma unroll
  for (int rs = 0; rs < 2; ++rs)
#pragma unroll
    for (int t = 0; t < 4; ++t) K[rs][t] = 0u;

  const uint_t jlane = (uint_t)(lg * 4);
  const int jt0 = jq * 16;
  for (int jt = jt0; jt < jt0 + 16; ++jt) {
    const int ka = bhbase + (jt * 16 + lr) * 64 + lg * 8;
    short8 kh0 = *(const short8*)(khi + ka);
    short8 kh1 = *(const short8*)(khi + ka + 32);
    short8 kl0 = *(const short8*)(klo + ka);
    short8 kl1 = *(const short8*)(klo + ka + 32);
    const uint_t jbase = (uint_t)(jt * 16) + jlane;
#pragma unroll
    for (int rs = 0; rs < 2; ++rs) {
      f32x4 aA = {0.f, 0.f, 0.f, 0.f};
      f32x4 aB = {0.f, 0.f, 0.f, 0.f};
      aA = __builtin_amdgcn_mfma_f32_16x16x32_bf16(kh0, qh[rs][0], aA, 0, 0, 0);
      aB = __builtin_amdgcn_mfma_f32_16x16x32_bf16(kh1, qh[rs][1], aB, 0, 0, 0);
      aA = __builtin_amdgcn_mfma_f32_16x16x32_bf16(kh0, ql[rs][0], aA, 0, 0, 0);
      aB = __builtin_amdgcn_mfma_f32_16x16x32_bf16(kh1, ql[rs][1], aB, 0, 0, 0);
      aA = __builtin_amdgcn_mfma_f32_16x16x32_bf16(kl0, qh[rs][0], aA, 0, 0, 0);
      aB = __builtin_amdgcn_mfma_f32_16x16x32_bf16(kl1, qh[rs][1], aB, 0, 0, 0);
#pragma unroll
      for (int t = 0; t < 4; ++t) {
        uint_t key = (mono_f32(aA[t] + aB[t]) & 0xFFFFFC00u) | (jbase + t);
        insk(key, K[rs][0], K[rs][1], K[rs][2], K[rs][3]);
      }
    }
  }

  // intra-wave merge of the 4 lane-groups (disjoint j subsets) per q-row
#pragma unroll
  for (int rs = 0; rs < 2; ++rs) {
#pragma unroll
    for (int mask = 16; mask <= 32; mask <<= 1) {
      uint_t o0 = __shfl_xor(K[rs][0], mask), o1 = __shfl_xor(K[rs][1], mask);
      uint_t o2 = __shfl_xor(K[rs][2], mask), o3 = __shfl_xor(K[rs][3], mask);
      insk(o0, K[rs][0], K[rs][1], K[rs][2], K[rs][3]);
      insk(o1, K[rs][0], K[rs][1], K[rs][2], K[rs][3]);
      insk(o2, K[rs][0], K[rs][1], K[rs][2], K[rs][3]);
      insk(o3, K[rs][0], K[rs][1], K[rs][2], K[rs][3]);
    }
    if (l < 16) {
      int r = rowhalf * 32 + rs * 16 + l;
      kL[jq][r][0] = K[rs][0]; kL[jq][r][1] = K[rs][1];
      kL[jq][r][2] = K[rs][2]; kL[jq][r][3] = K[rs][3];
    }
  }
  __syncthreads();

  // cross-quarter merge + softmax (one thread per row)
  if (tid < 64) {
    uint_t s0 = kL[0][tid][0], s1 = kL[0][tid][1], s2 = kL[0][tid][2],
           s3 = kL[0][tid][3];
#pragma unroll
    for (int q = 1; q < 4; ++q)
#pragma unroll
      for (int t = 0; t < 4; ++t) insk(kL[q][tid][t], s0, s1, s2, s3);
    float x0 = unmono_f32(s0 & 0xFFFFFC00u);
    float x1 = unmono_f32(s1 & 0xFFFFFC00u);
    float x2 = unmono_f32(s2 & 0xFFFFFC00u);
    float x3 = unmono_f32(s3 & 0xFFFFFC00u);
    float m = x0;  // keys sorted desc -> x0 is max
    float e0 = expf(x0 - m), e1 = expf(x1 - m);
    float e2 = expf(x2 - m), e3 = expf(x3 - m);
    float inv = 1.f / (e0 + e1 + e2 + e3);
    wgt[tid][0] = e0 * inv; wgt[tid][1] = e1 * inv;
    wgt[tid][2] = e2 * inv; wgt[tid][3] = e3 * inv;
    widx[tid][0] = (int)(s0 & 1023u); widx[tid][1] = (int)(s1 & 1023u);
    widx[tid][2] = (int)(s2 & 1023u); widx[tid][3] = (int)(s3 & 1023u);
  }
  __syncthreads();

  // Phase 3: lane = d; gather V, weight, multiply q, accumulate over rows
  const float* vbh = vg + (size_t)bhbase;
  float acc = 0.f;
#pragma unroll
  for (int rr = 0; rr < 8; ++rr) {
    int r = w * 8 + rr;
    float w0 = wgt[r][0], w1 = wgt[r][1], w2 = wgt[r][2], w3 = wgt[r][3];
    int x0 = widx[r][0], x1 = widx[r][1], x2 = widx[r][2], x3 = widx[r][3];
    float wv = w0 * vbh[(size_t)x0 * 64 + l];
    wv = fmaf(w1, vbh[(size_t)x1 * 64 + l], wv);
    wv = fmaf(w2, vbh[(size_t)x2 * 64 + l], wv);
    wv = fmaf(w3, vbh[(size_t)x3 * 64 + l], wv);
    int qa = bhbase + (rg * 64 + r) * 64 + l;
    float qv = bf2f(qhi[qa]) + bf2f(qlo[qa]);
    acc = fmaf(wv, qv, acc);
  }
  accb[w][l] = acc;
  __syncthreads();
  if (w == 0) {
    float tot = accb[0][l] + accb[1][l] + accb[2][l] + accb[3][l] +
                accb[4][l] + accb[5][l] + accb[6][l] + accb[7][l];
    int b = bh >> 3, hh = bh & 7;
    atomicAdd(&out[(size_t)b * Cc + l * Hc + hh], tot);
  }
}

// ---------------------------------------------------------------- launch
extern "C" void kernel_launch(void* const* d_in, const int* in_sizes, int n_in,
                              void* d_out, int out_size, void* d_ws,
                              size_t ws_size, hipStream_t stream) {
  (void)in_sizes; (void)n_in; (void)out_size; (void)ws_size;
  const float* x = (const float*)d_in[0];
  const float* wq = (const float*)d_in[1];
  const float* bias = (const float*)d_in[2];
  float* out = (float*)d_out;

  float* vbuf = (float*)d_ws;               // QSZ f32        (16.8 MB)
  ushort_t* khi = (ushort_t*)(vbuf + QSZ);  // QSZ bf16 each  (8.4 MB x4)
  ushort_t* klo = khi + QSZ;
  ushort_t* qhi = klo + QSZ;
  ushort_t* qlo = qhi + QSZ;
  ushort_t* xth = qlo + QSZ;                // XTSZ bf16 each (8.4 MB x2)
  ushort_t* xtl = xth + XTSZ;
  ushort_t* wth = xtl + XTSZ;               // WTSZ bf16 each (1.6 MB x2)
  ushort_t* wtl = wth + WTSZ;

  zero_out_k<<<dim3((Bc * Cc + 255) / 256), 256, 0, stream>>>(out);
  conv_x<<<dim3(16, 8, 8), 256, 0, stream>>>(x, xth, xtl);
  conv_w<<<dim3(24, 8), 256, 0, stream>>>(wq, wth, wtl);
  qkv_gemm_mfma<<<dim3(64, 12), 256, 0, stream>>>(
      xth, xtl, wth, wtl, bias, vbuf, khi, klo, qhi, qlo);
  attn_topk_mfma<<<dim3(1024), 512, 0, stream>>>(khi, klo, qhi, qlo, vbuf,
                                                 out);
}